// Round 11
// baseline (92.569 us; speedup 1.0000x reference)
//
#include <hip/hip_runtime.h>
#include <hip/hip_bf16.h>

#define NB 4
#define NH 12
#define SEQ 4096
#define DIM 64
#define LOG2E 1.4426950408889634f

typedef __attribute__((ext_vector_type(8))) short short8;
typedef __attribute__((ext_vector_type(4))) float f32x4;
typedef __attribute__((ext_vector_type(2))) unsigned int u32x2;

static __device__ __forceinline__ unsigned int pk2(float a, float b) {
    float2 t; t.x = a; t.y = b;
    union { __hip_bfloat162 h; unsigned int u; } x;
    x.h = __float22bfloat162_rn(t);
    return x.u;
}
static __device__ __forceinline__ short8 mk8(unsigned int a, unsigned int b,
                                             unsigned int c, unsigned int d) {
    union { unsigned int u[4]; short8 s; } x;
    x.u[0] = a; x.u[1] = b; x.u[2] = c; x.u[3] = d;
    return x.s;
}

__global__ __launch_bounds__(1024, 4)
void blk_attn(const float* __restrict__ Q, const float* __restrict__ K,
              const float* __restrict__ V, const float* __restrict__ M,
              float* __restrict__ O) {
    int bid = blockIdx.x;
    bid = (bid & 7) * 192 + (bid >> 3);   // XCD swizzle: resident set 2.2MB/XCD < 4MB L2

    const int j  = bid & 31;
    const int bh = bid >> 5;
    const int b  = bh / NH;

    const size_t base = (size_t)bh * SEQ * DIM;
    const float* Kp = K + base;
    const float* Vp = V + base;

    const int tid  = threadIdx.x;
    const int w    = tid >> 6;      // wave 0..15
    const int qg   = w >> 1;        // query group: 16 rows [128j+16qg, +16)
    const int h    = w & 1;         // key half: global tiles [12h, 12h+12)
    const int lane = tid & 63;
    const int lo   = lane & 15;
    const int hi   = lane >> 4;

    // span [kb0, kb0+384): W0 = tiles 0..15, W1 = tiles 8..23
    const int  kb0 = (j == 0) ? 0 : ((j == 31) ? SEQ - 384 : 128 * j - 128);
    const bool md  = (j != 0) && (j != 31);
    const float wt0 = (j == 31) ? 0.f : (md ? 0.5f : 1.f);
    const float wt1 = (j == 0)  ? 0.f : (md ? 0.5f : 1.f);

    // ---- LDS: 132 KB (1 block/CU, 16 waves = 4/SIMD) ----
    __shared__ __align__(16) unsigned char smem[135168];
    auto Ks = (unsigned short (*)[64])(smem);            // [384][64]: K[key][d ^ 8*(key&7)]
    auto Vt = (unsigned short (*)[384])(smem + 49152);   // [64][384]: V^T[d][k ^ 8*((d^(d>>2))&7)]
    auto Pw = (unsigned int (*)[16][32])(smem + 98304);  // [16 waves][16 q][32 dw]
    auto Sx = (float (*)[8][16][4])(smem + 131072);      // [h][qg][q=lo][m, S0c, S1c, -]
    auto Opart = (float (*)[16][68])(smem);              // [8 qg][16 q][68] alias (Ks dead)

    // ---- Q fragments, scaled by log2e/8 ----
    short8 qa[2];
    {
        const float qs = 0.125f * LOG2E;
        const float* qr = Q + base + (size_t)(128 * j + 16 * qg + lo) * DIM + hi * 8;
        #pragma unroll
        for (int s = 0; s < 2; ++s) {
            f32x4 a = *reinterpret_cast<const f32x4*>(qr + 32 * s);
            f32x4 c = *reinterpret_cast<const f32x4*>(qr + 32 * s + 4);
            qa[s] = mk8(pk2(a[0] * qs, a[1] * qs), pk2(a[2] * qs, a[3] * qs),
                        pk2(c[0] * qs, c[1] * qs), pk2(c[2] * qs, c[3] * qs));
        }
    }

    // ---- stage K: 384 rows across 16 waves, b128 conflict-free writes ----
    {
        const int c8 = lane & 7, r8 = lane >> 3;
        #pragma unroll
        for (int it = 0; it < 3; ++it) {
            const int row = 8 * w + r8 + 128 * it;       // row & 7 == r8
            const float* kp = Kp + (size_t)(kb0 + row) * DIM + 8 * c8;
            f32x4 a = *reinterpret_cast<const f32x4*>(kp);
            f32x4 c = *reinterpret_cast<const f32x4*>(kp + 4);
            *reinterpret_cast<short8*>(&Ks[row][(8 * c8) ^ (8 * r8)]) =
                mk8(pk2(a[0], a[1]), pk2(a[2], a[3]), pk2(c[0], c[1]), pk2(c[2], c[3]));
        }
    }
    // ---- stage V^T: 4x4 register transpose ----
    {
        const int quad = lane & 3, colq = lane >> 2;
        #pragma unroll
        for (int it = 0; it < 2; ++it) {
            const int kg = w + 16 * it;                  // wave-uniform
            if (kg < 24) {
                const int k0 = 16 * kg + 4 * quad;
                f32x4 vr[4];
                #pragma unroll
                for (int kk = 0; kk < 4; ++kk)
                    vr[kk] = *reinterpret_cast<const f32x4*>(
                        Vp + (size_t)(kb0 + k0 + kk) * DIM + 4 * colq);
                #pragma unroll
                for (int i = 0; i < 4; ++i) {
                    const int d  = 4 * colq + i;
                    const int gd = (d ^ (d >> 2)) & 7;
                    u32x2 o;
                    o[0] = pk2(vr[0][i], vr[1][i]);
                    o[1] = pk2(vr[2][i], vr[3][i]);
                    *reinterpret_cast<u32x2*>(&Vt[d][k0 ^ (8 * gd)]) = o;
                }
            }
        }
    }
    __syncthreads();   // barrier 1: staging complete

    // ---- QK^T swapped, this half's 12 tiles: st[l] -> S[key][q=lo] ----
    const int kb   = 192 * h;
    const int kswz = 8 * (lo & 7);
    f32x4 st[12];
    #pragma unroll
    for (int l = 0; l < 12; ++l) { st[l][0]=0.f; st[l][1]=0.f; st[l][2]=0.f; st[l][3]=0.f; }
    __builtin_amdgcn_s_setprio(1);
    #pragma unroll
    for (int s = 0; s < 2; ++s)
        #pragma unroll
        for (int l = 0; l < 12; ++l) {
            short8 kf = *reinterpret_cast<const short8*>(
                &Ks[kb + 16 * l + lo][(32 * s + 8 * hi) ^ kswz]);
            st[l] = __builtin_amdgcn_mfma_f32_16x16x32_bf16(kf, qa[s], st[l], 0, 0, 0);
        }
    __builtin_amdgcn_s_setprio(0);

    // ---- mask (global, L2-resident; pre-scaled by log2e) ----
    const float* Mq = M + (size_t)b * SEQ + kb0 + kb;
    #pragma unroll
    for (int l = 0; l < 12; ++l) {
        f32x4 mv = *reinterpret_cast<const f32x4*>(Mq + 16 * l + 4 * hi);
        #pragma unroll
        for (int r = 0; r < 4; ++r) st[l][r] = fmaf(mv[r], LOG2E, st[l][r]);
    }

    // ---- local softmax (single pass, q = lo lane-local) ----
    float mloc = st[0][0];
    #pragma unroll
    for (int l = 0; l < 12; ++l)
        #pragma unroll
        for (int r = 0; r < 4; ++r) mloc = fmaxf(mloc, st[l][r]);
    mloc = fmaxf(mloc, __shfl_xor(mloc, 16));
    mloc = fmaxf(mloc, __shfl_xor(mloc, 32));
    #pragma unroll
    for (int l = 0; l < 12; ++l)
        #pragma unroll
        for (int r = 0; r < 4; ++r) st[l][r] = exp2f(st[l][r] - mloc);

    float sa = 0.f, sp = 0.f;   // all 12 tiles; overlap part (h0: l>=8, h1: l<4)
    #pragma unroll
    for (int l = 0; l < 12; ++l) {
        const float t = (st[l][0] + st[l][1]) + (st[l][2] + st[l][3]);
        sa += t;
        if (h == 0) { if (l >= 8) sp += t; }
        else        { if (l < 4)  sp += t; }
    }
    sa += __shfl_xor(sa, 16); sa += __shfl_xor(sa, 32);
    sp += __shfl_xor(sp, 16); sp += __shfl_xor(sp, 32);

    if (hi == 0) {
        Sx[h][qg][lo][0] = mloc;
        Sx[h][qg][lo][1] = h ? sp : sa;   // contribution to S0 (W0)
        Sx[h][qg][lo][2] = h ? sa : sp;   // contribution to S1 (W1)
    }
    __syncthreads();   // barrier 2: Sx exchange (Ks now dead -> Opart aliases it)

    // ---- merge stats with partner half (all lane-local, q = lo) ----
    const float mo  = Sx[1 - h][qg][lo][0];
    const float s0o = Sx[1 - h][qg][lo][1];
    const float s1o = Sx[1 - h][qg][lo][2];
    const float s0l = h ? sp : sa;
    const float s1l = h ? sa : sp;
    const float mu  = fmaxf(mloc, mo);
    const float scm = exp2f(mloc - mu);
    const float sco = exp2f(mo - mu);
    const float S0  = fmaf(s0l, scm, s0o * sco);
    const float S1  = fmaf(s1l, scm, s1o * sco);
    const float b0  = wt0 * scm / S0;
    const float b1  = wt1 * scm / S1;
    float cz[3];
    cz[0] = h ? (b0 + b1) : b0;   // l 0-3   (h1: global 12-15 in both windows)
    cz[1] = h ? b1 : b0;          // l 4-7
    cz[2] = h ? b1 : (b0 + b1);   // l 8-11  (h0: global 8-11 in both windows)

    // ---- PV swapped (O^T, q = lo), coefficients pre-folded into P ----
    f32x4 acc[4];
    #pragma unroll
    for (int dt = 0; dt < 4; ++dt) { acc[dt][0]=0.f; acc[dt][1]=0.f; acc[dt][2]=0.f; acc[dt][3]=0.f; }
    const int pswz = 4 * (lo & 7);

    #pragma unroll
    for (int kq = 0; kq < 6; ++kq) {
        const int pp = 16 * (kq & 1);
        const float cA = cz[(2 * kq) >> 2];
        const float cB = cz[(2 * kq + 1) >> 2];
        u32x2 w0v, w1v;
        w0v[0] = pk2(st[2 * kq][0] * cA, st[2 * kq][1] * cA);
        w0v[1] = pk2(st[2 * kq][2] * cA, st[2 * kq][3] * cA);
        w1v[0] = pk2(st[2 * kq + 1][0] * cB, st[2 * kq + 1][1] * cB);
        w1v[1] = pk2(st[2 * kq + 1][2] * cB, st[2 * kq + 1][3] * cB);
        *reinterpret_cast<u32x2*>(&Pw[w][lo][(pp + 2 * hi)     ^ pswz]) = w0v;
        *reinterpret_cast<u32x2*>(&Pw[w][lo][(pp + 8 + 2 * hi) ^ pswz]) = w1v;
        short8 pf = *reinterpret_cast<const short8*>(&Pw[w][lo][(pp + 4 * hi) ^ pswz]);
        __builtin_amdgcn_s_setprio(1);
        #pragma unroll
        for (int dt = 0; dt < 4; ++dt) {
            const int d  = 16 * dt + lo;
            const int gd = (d ^ (d >> 2)) & 7;
            short8 vf = *reinterpret_cast<const short8*>(
                &Vt[d][(kb + 32 * kq + 8 * hi) ^ (8 * gd)]);
            acc[dt] = __builtin_amdgcn_mfma_f32_16x16x32_bf16(vf, pf, acc[dt], 0, 0, 0);
        }
        __builtin_amdgcn_s_setprio(0);
    }

    // ---- combine halves: h0 -> Opart (aliases dead Ks), h1 adds + stores ----
    if (h == 0) {
        #pragma unroll
        for (int dt = 0; dt < 4; ++dt)
            *reinterpret_cast<f32x4*>(&Opart[qg][lo][16 * dt + 4 * hi]) = acc[dt];
    }
    __syncthreads();   // barrier 3
    if (h == 1) {
        float* Opr = O + base + (size_t)(128 * j + 16 * qg + lo) * DIM + 4 * hi;
        #pragma unroll
        for (int dt = 0; dt < 4; ++dt) {
            f32x4 pv = *reinterpret_cast<const f32x4*>(&Opart[qg][lo][16 * dt + 4 * hi]);
            f32x4 o;
            #pragma unroll
            for (int r = 0; r < 4; ++r) o[r] = acc[dt][r] + pv[r];
            *reinterpret_cast<f32x4*>(Opr + 16 * dt) = o;
        }
    }
}

extern "C" void kernel_launch(void* const* d_in, const int* in_sizes, int n_in,
                              void* d_out, int out_size, void* d_ws, size_t ws_size,
                              hipStream_t stream) {
    const float* Q = (const float*)d_in[0];
    const float* K = (const float*)d_in[1];
    const float* V = (const float*)d_in[2];
    const float* M = (const float*)d_in[3];
    float* O = (float*)d_out;
    blk_attn<<<dim3(NB * NH * (SEQ / 128)), dim3(1024), 0, stream>>>(Q, K, V, M, O);
}